// Round 1
// baseline (37.901 us; speedup 1.0000x reference)
//
#include <hip/hip_runtime.h>

// Problem constants: a,p,n are [16,3,512,512] f32.
// H=W=512, window=128x128, stride 64 -> 8x8 grid of 64x64 base blocks.
#define HH 512
#define WW 512
#define BC 48            // B*C = 16*3
#define NBLK 64          // 8x8 base blocks per image
#define TOTAL_PIX 12582912.0f   // 16*3*512*512

// Kernel 1: per-base-block sums of |n-a| and |a-p|.
// grid = BC*NBLK = 3072 blocks, 256 threads each. Each thread: 4 float4 per input.
__global__ __launch_bounds__(256) void hd_block_sums(
    const float* __restrict__ a, const float* __restrict__ p,
    const float* __restrict__ n,
    float* __restrict__ blk_na, float* __restrict__ blk_ap)
{
    const int gb  = blockIdx.x;       // 0..3071
    const int bc  = gb >> 6;
    const int blk = gb & 63;
    const int bi = blk >> 3, bj = blk & 7;
    const int tid = threadIdx.x;

    const size_t img = (size_t)bc * (HH * WW);
    const int row0 = bi * 64, col0 = bj * 64;

    float s1 = 0.f, s2 = 0.f;
    // 64x64 block = 1024 float4s; thread t handles f = t + k*256
    #pragma unroll
    for (int k = 0; k < 4; ++k) {
        int f = tid + (k << 8);
        int r = f >> 4;               // 16 float4 per 64-float row
        int c = (f & 15) << 2;
        size_t idx = img + (size_t)(row0 + r) * WW + (col0 + c);
        float4 va = *reinterpret_cast<const float4*>(a + idx);
        float4 vp = *reinterpret_cast<const float4*>(p + idx);
        float4 vn = *reinterpret_cast<const float4*>(n + idx);
        s1 += fabsf(vn.x - va.x) + fabsf(vn.y - va.y)
            + fabsf(vn.z - va.z) + fabsf(vn.w - va.w);
        s2 += fabsf(va.x - vp.x) + fabsf(va.y - vp.y)
            + fabsf(va.z - vp.z) + fabsf(va.w - vp.w);
    }

    // wave(64) shuffle reduce
    #pragma unroll
    for (int off = 32; off > 0; off >>= 1) {
        s1 += __shfl_xor(s1, off, 64);
        s2 += __shfl_xor(s2, off, 64);
    }
    __shared__ float r1[4], r2[4];
    const int wave = tid >> 6, lane = tid & 63;
    if (lane == 0) { r1[wave] = s1; r2[wave] = s2; }
    __syncthreads();
    if (tid == 0) {
        blk_na[gb] = r1[0] + r1[1] + r1[2] + r1[3];
        blk_ap[gb] = r2[0] + r2[1] + r2[2] + r2[3];
    }
}

// Kernel 2: tiny finalize. 1 block, 256 threads = 4 waves; each wave handles
// one (b,c) per iteration (12 iterations). Writes scalar loss to out[0].
__global__ __launch_bounds__(256) void hd_finalize(
    const float* __restrict__ blk_na, const float* __restrict__ blk_ap,
    float* __restrict__ out)
{
    __shared__ float sblk[4][64];
    __shared__ float swv[4][64];
    __shared__ float partial[4];
    const int tid  = threadIdx.x;
    const int wid  = tid >> 6;        // wave id 0..3
    const int lane = tid & 63;
    const int i = lane >> 3, j = lane & 7;

    float acc = 0.f;
    #pragma unroll 1
    for (int iter = 0; iter < 12; ++iter) {
        const int bc = iter * 4 + wid;
        float b  = blk_na[bc * 64 + lane];
        float bp = blk_ap[bc * 64 + lane];
        sblk[wid][lane] = b;
        // diff = sum over the 8x8 grid (wave reduce)
        float d = b;
        #pragma unroll
        for (int off = 32; off > 0; off >>= 1) d += __shfl_xor(d, off, 64);
        __syncthreads();
        // window values wv[i][j] for i,j in [0,7); zero elsewhere
        float w = 0.f;
        if (i < 7 && j < 7) {
            w = (sblk[wid][i * 8 + j]     + sblk[wid][(i + 1) * 8 + j] +
                 sblk[wid][i * 8 + j + 1] + sblk[wid][(i + 1) * 8 + j + 1]) / d;
        }
        swv[wid][lane] = w;
        __syncthreads();
        // overlap-add: mask_blk[i][j] = sum wv[i'][j'], i' in {i-1,i}, j' in {j-1,j}
        // (swv is zero at i==7 / j==7, so only negative indices need guards)
        float mb = swv[wid][i * 8 + j];
        if (i > 0)          mb += swv[wid][(i - 1) * 8 + j];
        if (j > 0)          mb += swv[wid][i * 8 + j - 1];
        if (i > 0 && j > 0) mb += swv[wid][(i - 1) * 8 + j - 1];
        const int ci = (i == 0 || i == 7) ? 1 : 2;
        const int cj = (j == 0 || j == 7) ? 1 : 2;
        acc += (mb / (float)(ci * cj)) * bp;
        __syncthreads();   // protect sblk/swv before next iteration overwrites
    }

    #pragma unroll
    for (int off = 32; off > 0; off >>= 1) acc += __shfl_xor(acc, off, 64);
    if (lane == 0) partial[wid] = acc;
    __syncthreads();
    if (tid == 0)
        out[0] = (partial[0] + partial[1] + partial[2] + partial[3]) / TOTAL_PIX;
}

extern "C" void kernel_launch(void* const* d_in, const int* in_sizes, int n_in,
                              void* d_out, int out_size, void* d_ws, size_t ws_size,
                              hipStream_t stream) {
    const float* a = (const float*)d_in[0];
    const float* p = (const float*)d_in[1];
    const float* n = (const float*)d_in[2];
    float* blk_na = (float*)d_ws;                 // 3072 floats
    float* blk_ap = blk_na + BC * NBLK;           // 3072 floats

    hd_block_sums<<<BC * NBLK, 256, 0, stream>>>(a, p, n, blk_na, blk_ap);
    hd_finalize<<<1, 256, 0, stream>>>(blk_na, blk_ap, (float*)d_out);
}

// Round 2
// 31.367 us; speedup vs baseline: 1.2083x; 1.2083x over previous
//
#include <hip/hip_runtime.h>

// a,p,n: [16,3,512,512] f32. H=W=512; window 128x128 stride 64 ->
// 8x8 grid of 64x64 base blocks per (b,c) image.
#define WW 512
#define IMG_F 262144            // 512*512 floats per (b,c)
#define BC 48                   // 16*3
#define NBLK 64                 // 8x8 base blocks
#define TOTAL_PIX 12582912.0f   // 16*3*512*512

// Kernel 1: per-base-block sums of |n-a| and |a-p|.
// grid = 3072 blocks x 256 threads. All 12 float4 loads issued before any
// accumulation -> 12-deep memory-level parallelism per thread.
__global__ __launch_bounds__(256) void hd_block_sums(
    const float* __restrict__ a, const float* __restrict__ p,
    const float* __restrict__ n,
    float* __restrict__ blk_na, float* __restrict__ blk_ap)
{
    const int gb  = blockIdx.x;       // 0..3071
    const int bc  = gb >> 6;
    const int blk = gb & 63;
    const int bi = blk >> 3, bj = blk & 7;
    const int tid = threadIdx.x;

    // thread t, step k: row = bi*64 + (t>>4) + 16k, col = bj*64 + (t&15)*4
    const size_t idx0 = (size_t)bc * IMG_F
                      + (size_t)(bi * 64 + (tid >> 4)) * WW
                      + (size_t)(bj * 64 + ((tid & 15) << 2));
    const float* pa = a + idx0;
    const float* pp = p + idx0;
    const float* pn = n + idx0;

    // 16 rows per step = 8192 floats
    float4 va0 = *(const float4*)(pa);
    float4 va1 = *(const float4*)(pa + 8192);
    float4 va2 = *(const float4*)(pa + 16384);
    float4 va3 = *(const float4*)(pa + 24576);
    float4 vn0 = *(const float4*)(pn);
    float4 vn1 = *(const float4*)(pn + 8192);
    float4 vn2 = *(const float4*)(pn + 16384);
    float4 vn3 = *(const float4*)(pn + 24576);
    float4 vp0 = *(const float4*)(pp);
    float4 vp1 = *(const float4*)(pp + 8192);
    float4 vp2 = *(const float4*)(pp + 16384);
    float4 vp3 = *(const float4*)(pp + 24576);

    float s1, s2;
    s1  = fabsf(vn0.x - va0.x) + fabsf(vn0.y - va0.y) + fabsf(vn0.z - va0.z) + fabsf(vn0.w - va0.w);
    s1 += fabsf(vn1.x - va1.x) + fabsf(vn1.y - va1.y) + fabsf(vn1.z - va1.z) + fabsf(vn1.w - va1.w);
    s1 += fabsf(vn2.x - va2.x) + fabsf(vn2.y - va2.y) + fabsf(vn2.z - va2.z) + fabsf(vn2.w - va2.w);
    s1 += fabsf(vn3.x - va3.x) + fabsf(vn3.y - va3.y) + fabsf(vn3.z - va3.z) + fabsf(vn3.w - va3.w);
    s2  = fabsf(va0.x - vp0.x) + fabsf(va0.y - vp0.y) + fabsf(va0.z - vp0.z) + fabsf(va0.w - vp0.w);
    s2 += fabsf(va1.x - vp1.x) + fabsf(va1.y - vp1.y) + fabsf(va1.z - vp1.z) + fabsf(va1.w - vp1.w);
    s2 += fabsf(va2.x - vp2.x) + fabsf(va2.y - vp2.y) + fabsf(va2.z - vp2.z) + fabsf(va2.w - vp2.w);
    s2 += fabsf(va3.x - vp3.x) + fabsf(va3.y - vp3.y) + fabsf(va3.z - vp3.z) + fabsf(va3.w - vp3.w);

    #pragma unroll
    for (int off = 32; off > 0; off >>= 1) {
        s1 += __shfl_xor(s1, off, 64);
        s2 += __shfl_xor(s2, off, 64);
    }
    __shared__ float r1[4], r2[4];
    const int wave = tid >> 6, lane = tid & 63;
    if (lane == 0) { r1[wave] = s1; r2[wave] = s2; }
    __syncthreads();
    if (tid == 0) {
        blk_na[gb] = r1[0] + r1[1] + r1[2] + r1[3];
        blk_ap[gb] = r2[0] + r2[1] + r2[2] + r2[3];
    }
}

// Kernel 2: finalize. One wave per (b,c); 64 lanes = the 8x8 block grid.
// Pure shuffle math, no per-iteration barriers. 1 block x 1024 threads,
// 16 waves x 3 rounds = 48 (b,c) pairs.
__global__ __launch_bounds__(1024) void hd_finalize(
    const float* __restrict__ blk_na, const float* __restrict__ blk_ap,
    float* __restrict__ out)
{
    const int tid  = threadIdx.x;
    const int w    = tid >> 6;        // wave 0..15
    const int lane = tid & 63;
    const int i = lane >> 3, j = lane & 7;
    __shared__ float partial[16];

    float acc = 0.f;
    #pragma unroll
    for (int it = 0; it < 3; ++it) {
        const int bc = w + it * 16;
        float b  = blk_na[bc * 64 + lane];
        float bp = blk_ap[bc * 64 + lane];
        // diff = sum over 8x8 grid
        float d = b;
        #pragma unroll
        for (int off = 32; off > 0; off >>= 1) d += __shfl_xor(d, off, 64);
        // window value wv[i][j], defined for i,j<7 (else 0)
        float b_r  = __shfl(b, lane + 8, 64);   // blk[i+1][j]
        float b_c  = __shfl(b, lane + 1, 64);   // blk[i][j+1]
        float b_rc = __shfl(b, lane + 9, 64);   // blk[i+1][j+1]
        float wv = (i < 7 && j < 7) ? (b + b_r + b_c + b_rc) / d : 0.f;
        // overlap-add: mb[i][j] = wv[i][j] + wv[i-1][j] + wv[i][j-1] + wv[i-1][j-1]
        float wv_u  = __shfl(wv, lane - 8, 64);
        float wv_l  = __shfl(wv, lane - 1, 64);
        float wv_ul = __shfl(wv, lane - 9, 64);
        float mb = wv;
        if (i > 0)          mb += wv_u;
        if (j > 0)          mb += wv_l;
        if (i > 0 && j > 0) mb += wv_ul;
        const int ci = (i == 0 || i == 7) ? 1 : 2;
        const int cj = (j == 0 || j == 7) ? 1 : 2;
        acc += (mb / (float)(ci * cj)) * bp;
    }

    #pragma unroll
    for (int off = 32; off > 0; off >>= 1) acc += __shfl_xor(acc, off, 64);
    if (lane == 0) partial[w] = acc;
    __syncthreads();
    if (tid == 0) {
        float s = 0.f;
        #pragma unroll
        for (int k = 0; k < 16; ++k) s += partial[k];
        out[0] = s / TOTAL_PIX;
    }
}

extern "C" void kernel_launch(void* const* d_in, const int* in_sizes, int n_in,
                              void* d_out, int out_size, void* d_ws, size_t ws_size,
                              hipStream_t stream) {
    const float* a = (const float*)d_in[0];
    const float* p = (const float*)d_in[1];
    const float* n = (const float*)d_in[2];
    float* blk_na = (float*)d_ws;                 // 3072 floats
    float* blk_ap = blk_na + BC * NBLK;           // 3072 floats

    hd_block_sums<<<BC * NBLK, 256, 0, stream>>>(a, p, n, blk_na, blk_ap);
    hd_finalize<<<1, 1024, 0, stream>>>(blk_na, blk_ap, (float*)d_out);
}